// Round 7
// baseline (175.687 us; speedup 1.0000x reference)
//
#include <hip/hip_runtime.h>

#define IMG_H 4096
#define IMG_W 4096
#define RPT 4                 // rows per wave
#define WPR (IMG_W / 256)     // waves per row strip

typedef float floatx4 __attribute__((ext_vector_type(4)));
typedef int   intx4   __attribute__((ext_vector_type(4)));

// Bounds-checked buffer loads (MUBUF SRD): OOB lanes return 0.0 and never
// fault. Volatile asm loads have fixed mutual order: all issue back-to-back,
// one vmcnt(0) wait, then pure VALU.
__device__ __forceinline__ floatx4 bload(intx4 rsrc, int voff) {
    floatx4 d;
    asm volatile("buffer_load_dwordx4 %0, %1, %2, 0 offen"
                 : "=v"(d) : "v"(voff), "s"(rsrc));
    return d;
}
__device__ __forceinline__ floatx4 bload_nt(intx4 rsrc, int voff) {
    floatx4 d;
    asm volatile("buffer_load_dwordx4 %0, %1, %2, 0 offen nt"
                 : "=v"(d) : "v"(voff), "s"(rsrc));
    return d;
}

// Branch selection equivalent (verified bit-exact by boundary ulp-analysis) to:
//   q = rintf(deg/45.f)*45.f;  q==180 -> 0;  chain-compare 0/45/90/else.
__device__ __forceinline__ float nms_px(float t, bool interior,
                                        float uL, float uC, float uR,
                                        float cL, float cC, float cR,
                                        float dL, float dC, float dR) {
    float deg = t * 57.29577951308232f;        // float32(180/pi)
    deg = (deg < 0.0f) ? deg + 180.0f : deg;   // same fp32 add as reference
    const bool is0  = (deg >= -22.5f && deg <= 22.5f) || (deg >= 157.5f && deg <= 202.5f);
    const bool is45 = (deg >  22.5f) && (deg <  67.5f);
    const bool is90 = (deg >= 67.5f) && (deg <= 112.5f);
    const float a = is0 ? cR : (is45 ? dR : (is90 ? dC : dL));
    const float b = is0 ? cL : (is45 ? uL : (is90 ? uC : uR));
    return ((cC >= a) && (cC >= b) && interior) ? cC : 0.0f;
}

// Evidence ledger:
//  r0-r6: dispatch time pinned 52-56us across: 2x occupancy (r1), forced
//    issue-all/wait-once MLP (r5), 2x total vector-memory bytes (r0 vs r5),
//    cached vs NT stores (r6: WRITE_SIZE 64MB either way). HBM traffic is
//    structural at ~128MB (theta read + out write) and stuck at ~2.5 TB/s —
//    consistent with a latency x outstanding-miss clamp on the NT read path.
//    m13's CACHED streaming copy reaches 6.3 TB/s on this chip, and r3's
//    "cache theta" regression was confounded (img also occupied L2 there).
//  r7 single change vs r5: SWAP read policies — theta CACHED (allocating,
//    stream-friendly miss path, L2 to itself), img NT (it's L3-resident;
//    NT still probes/hits caches, just doesn't allocate). Stores stay NT.
__global__ __launch_bounds__(256, 4) void nms_kernel(const float* __restrict__ img,
                                                     const float* __restrict__ theta,
                                                     float* __restrict__ out) {
    // XCD-aware remap: 4096 blocks, blk%8 = XCD -> 8 horizontal bands of 512 rows.
    const int xcd  = blockIdx.x & 7;
    const int slot = blockIdx.x >> 3;          // 0..511 within band
    const int g    = xcd * (IMG_H / RPT / 8) + (slot >> 2);   // row-group
    const int seg  = (slot & 3) * 4 + (threadIdx.x >> 6);     // col segment 0..15
    const int lane = threadIdx.x & 63;

    const int y4 = (seg << 8) + (lane << 2);   // this lane's 4-px chunk
    const int x0 = g * RPT;

    intx4 rimg, rth;
    rimg.x = (int)(uintptr_t)img;
    rimg.y = (int)(((uintptr_t)img) >> 32) & 0xFFFF;
    rimg.z = IMG_H * IMG_W * 4;                // num_records (bytes)
    rimg.w = 0x00020000;                       // raw dword SRD
    rth.x  = (int)(uintptr_t)theta;
    rth.y  = (int)(((uintptr_t)theta) >> 32) & 0xFFFF;
    rth.z  = IMG_H * IMG_W * 4;
    rth.w  = 0x00020000;

    floatx4 a[RPT + 2], m[RPT + 2], p[RPT + 2], th[RPT];

    // ---- issue ALL loads back-to-back (theta first: HBM, longest latency) ----
    #pragma unroll
    for (int i = 0; i < RPT; ++i)
        th[i] = bload(rth, ((x0 + i) * IMG_W + y4) * 4);      // CACHED (r7 change)

    const int base = ((x0 - 1) * IMG_W + y4) * 4;  // byte offset, row x0-1
    #pragma unroll
    for (int k = 0; k < RPT + 2; ++k) {
        const int ro = base + k * (IMG_W * 4);
        a[k] = bload_nt(rimg, ro);                            // NT (r7 change)
        m[k] = bload_nt(rimg, ro - 4);
        p[k] = bload_nt(rimg, ro + 4);
    }

    // ---- single wait; sched_barrier stops hipcc hoisting uses above it ----
    asm volatile("s_waitcnt vmcnt(0)" ::: "memory");
    __builtin_amdgcn_sched_barrier(0);

    // ---- border-column component fixes (2 lanes per wave-row at most) ----
    const bool eL = (y4 == 0);
    const bool eR = (y4 == IMG_W - 4);
    #pragma unroll
    for (int k = 0; k < RPT + 2; ++k) {
        m[k].y = eL ? a[k].x : m[k].y;
        m[k].z = eL ? a[k].y : m[k].z;
        m[k].w = eL ? a[k].z : m[k].w;
        p[k].x = eR ? a[k].y : p[k].x;
        p[k].y = eR ? a[k].z : p[k].y;
        p[k].z = eR ? a[k].w : p[k].z;
    }

    const bool c0_int = (y4 > 0);
    const bool c3_int = (y4 + 4 < IMG_W);

    // ---- pure-VALU compute + NT stores ----
    #pragma unroll
    for (int i = 0; i < RPT; ++i) {
        const int x = x0 + i;
        const bool row_int = (x > 0) && (x < IMG_H - 1);
        const floatx4 t = th[i];

        floatx4 o;
        o.x = nms_px(t.x, row_int && c0_int,
                     m[i].x, a[i].x, p[i].x,
                     m[i+1].x, a[i+1].x, p[i+1].x,
                     m[i+2].x, a[i+2].x, p[i+2].x);
        o.y = nms_px(t.y, row_int,
                     m[i].y, a[i].y, p[i].y,
                     m[i+1].y, a[i+1].y, p[i+1].y,
                     m[i+2].y, a[i+2].y, p[i+2].y);
        o.z = nms_px(t.z, row_int,
                     m[i].z, a[i].z, p[i].z,
                     m[i+1].z, a[i+1].z, p[i+1].z,
                     m[i+2].z, a[i+2].z, p[i+2].z);
        o.w = nms_px(t.w, row_int && c3_int,
                     m[i].w, a[i].w, p[i].w,
                     m[i+1].w, a[i+1].w, p[i+1].w,
                     m[i+2].w, a[i+2].w, p[i+2].w);

        floatx4* po = (floatx4*)(out + (size_t)x * IMG_W + y4);
        __builtin_nontemporal_store(o, po);
    }
}

extern "C" void kernel_launch(void* const* d_in, const int* in_sizes, int n_in,
                              void* d_out, int out_size, void* d_ws, size_t ws_size,
                              hipStream_t stream) {
    const float* img   = (const float*)d_in[0];
    const float* theta = (const float*)d_in[1];
    float* out = (float*)d_out;

    const int total_threads = (IMG_H / RPT) * WPR * 64;  // 1024 * 16 * 64
    const int block = 256;
    const int grid = total_threads / block;               // 4096
    nms_kernel<<<grid, block, 0, stream>>>(img, theta, out);
}

// Round 8
// 168.004 us; speedup vs baseline: 1.0457x; 1.0457x over previous
//
#include <hip/hip_runtime.h>

#define IMG_H 4096
#define IMG_W 4096
#define RPT 8                 // rows per wave: two 4-row pipelined halves
#define WPR (IMG_W / 256)

typedef float floatx4 __attribute__((ext_vector_type(4)));
typedef int   intx4   __attribute__((ext_vector_type(4)));

// All VMEM as volatile asm: fixed mutual issue order => exact vmcnt counting.
// Buffer SRD bounds-check: OOB returns 0 / store dropped (never faults) —
// halo rows x=-1, x=4096 come back 0 and feed only border-masked outputs.
__device__ __forceinline__ floatx4 bload4(intx4 rsrc, int voff) {
    floatx4 d;
    asm volatile("buffer_load_dwordx4 %0, %1, %2, 0 offen"
                 : "=v"(d) : "v"(voff), "s"(rsrc));
    return d;
}
__device__ __forceinline__ floatx4 bload4_nt(intx4 rsrc, int voff) {
    floatx4 d;
    asm volatile("buffer_load_dwordx4 %0, %1, %2, 0 offen nt"
                 : "=v"(d) : "v"(voff), "s"(rsrc));
    return d;
}
__device__ __forceinline__ float bload1(intx4 rsrc, int voff) {
    float d;
    asm volatile("buffer_load_dword %0, %1, %2, 0 offen"
                 : "=v"(d) : "v"(voff), "s"(rsrc));
    return d;
}
__device__ __forceinline__ void bstore4_nt(intx4 rsrc, int voff, floatx4 v) {
    asm volatile("buffer_store_dwordx4 %0, %1, %2, 0 offen nt"
                 :: "v"(v), "v"(voff), "s"(rsrc) : "memory");
}

// Branch selection equivalent (verified bit-exact by boundary ulp-analysis) to:
//   q = rintf(deg/45.f)*45.f;  q==180 -> 0;  chain-compare 0/45/90/else.
__device__ __forceinline__ float nms_px(float t, bool interior,
                                        float uL, float uC, float uR,
                                        float cL, float cC, float cR,
                                        float dL, float dC, float dR) {
    float deg = t * 57.29577951308232f;        // float32(180/pi)
    deg = (deg < 0.0f) ? deg + 180.0f : deg;   // same fp32 add as reference
    const bool is0  = (deg >= -22.5f && deg <= 22.5f) || (deg >= 157.5f && deg <= 202.5f);
    const bool is45 = (deg >  22.5f) && (deg <  67.5f);
    const bool is90 = (deg >= 67.5f) && (deg <= 112.5f);
    const float a = is0 ? cR : (is45 ? dR : (is90 ? dC : dL));
    const float b = is0 ? cL : (is45 ? uL : (is90 ? uC : uR));
    return ((cC >= a) && (cC >= b) && interior) ? cC : 0.0f;
}

// Evidence ledger:
//  r0-r7: dispatch pinned 52-56us across 2x occupancy, forced wait-once MLP,
//    2x vector-byte count, and the FULL read/write cache-policy matrix
//    (best: theta NT + img cached + out NT = r5). HBM-missing traffic
//    structural at ~128MB @ ~2.5 TB/s. Remaining suspect vs m13's 6.3 TB/s
//    copy: BURST-PHASE SYNC — resident blocks issue/stall/compute in
//    lockstep, memory idles during the synchronized compute phases.
//  r8: intra-wave 2-stage pipeline (counted vmcnt, all-asm VMEM): loads for
//    half1 stay in flight UNDER half0's compute+stores => continuous issue.
__global__ __launch_bounds__(256, 2) void nms_kernel(const float* __restrict__ img,
                                                     const float* __restrict__ theta,
                                                     float* __restrict__ out) {
    // XCD-aware remap: 2048 blocks, blk%8 = XCD -> 8 bands of 512 rows.
    const int xcd  = blockIdx.x & 7;
    const int slot = blockIdx.x >> 3;          // 0..255 within band
    const int g    = xcd * 64 + (slot >> 2);   // row-group 0..511 (8 rows each)
    const int seg  = (slot & 3) * 4 + (threadIdx.x >> 6);  // col segment 0..15
    const int lane = threadIdx.x & 63;

    const int wc = seg << 8;
    const int y4 = wc + (lane << 2);
    const int x0 = g * RPT;

    const bool is_l = (lane == 0);
    const bool is_r = (lane == 63);
    const int ye = is_l ? (wc > 0 ? wc - 1 : 0)
                        : (wc + 256 < IMG_W ? wc + 256 : IMG_W - 1);

    const bool c0_int = (y4 > 0);
    const bool c3_int = (y4 + 4 < IMG_W);

    intx4 rimg, rth, rout;
    rimg.x = (int)(uintptr_t)img;
    rimg.y = (int)(((uintptr_t)img) >> 32) & 0xFFFF;
    rimg.z = IMG_H * IMG_W * 4;
    rimg.w = 0x00020000;
    rth.x  = (int)(uintptr_t)theta;
    rth.y  = (int)(((uintptr_t)theta) >> 32) & 0xFFFF;
    rth.z  = IMG_H * IMG_W * 4;
    rth.w  = 0x00020000;
    rout.x = (int)(uintptr_t)out;
    rout.y = (int)(((uintptr_t)out) >> 32) & 0xFFFF;
    rout.z = IMG_H * IMG_W * 4;
    rout.w = 0x00020000;

    floatx4 r[RPT + 2];   // img rows x0-1 .. x0+8
    float   e[RPT + 2];   // edge-neighbor column per row
    floatx4 th[RPT];

    const int rowb  = IMG_W * 4;
    const int base  = (x0 - 1) * rowb + y4 * 4;   // row idx k at base + k*rowb
    const int ebase = (x0 - 1) * rowb + ye * 4;

    // ---- group 1: theta half0 (4 NT) ----
    #pragma unroll
    for (int i = 0; i < 4; ++i)
        th[i] = bload4_nt(rth, (x0 + i) * rowb + y4 * 4);
    // ---- group 2: img rows idx 0..5 (6x dwordx4 + 6x dword = 12) ----
    #pragma unroll
    for (int k = 0; k < 6; ++k) {
        r[k] = bload4(rimg, base + k * rowb);
        e[k] = bload1(rimg, ebase + k * rowb);
    }
    // ---- group 3: theta half1 (4 NT) ----
    #pragma unroll
    for (int i = 4; i < 8; ++i)
        th[i] = bload4_nt(rth, (x0 + i) * rowb + y4 * 4);
    // ---- group 4: img rows idx 6..9 (4+4 = 8) ----
    #pragma unroll
    for (int k = 6; k < 10; ++k) {
        r[k] = bload4(rimg, base + k * rowb);
        e[k] = bload1(rimg, ebase + k * rowb);
    }

    // ---- wait for groups 1+2 only; groups 3+4 (12 ops) stay in flight ----
    asm volatile("s_waitcnt vmcnt(12)" ::: "memory");
    __builtin_amdgcn_sched_barrier(0);

    // ---- half0: rows x0..x0+3 (uses r/e idx 0..5), overlapped with g3+g4 ----
    #pragma unroll
    for (int i = 0; i < 4; ++i) {
        const int x = x0 + i;
        const floatx4 u = r[i],   c = r[i + 1], d = r[i + 2];
        const float  ue = e[i],  ce = e[i + 1], de = e[i + 2];
        const floatx4 t = th[i];

        const float uLs = __shfl_up(u.w, 1, 64), uRs = __shfl_down(u.x, 1, 64);
        const float cLs = __shfl_up(c.w, 1, 64), cRs = __shfl_down(c.x, 1, 64);
        const float dLs = __shfl_up(d.w, 1, 64), dRs = __shfl_down(d.x, 1, 64);
        const float uL = is_l ? ue : uLs, uR = is_r ? ue : uRs;
        const float cL = is_l ? ce : cLs, cR = is_r ? ce : cRs;
        const float dL = is_l ? de : dLs, dR = is_r ? de : dRs;

        const bool row_int = (x > 0) && (x < IMG_H - 1);

        floatx4 o;
        o.x = nms_px(t.x, row_int && c0_int, uL,  u.x, u.y,  cL,  c.x, c.y,  dL,  d.x, d.y);
        o.y = nms_px(t.y, row_int,           u.x, u.y, u.z,  c.x, c.y, c.z,  d.x, d.y, d.z);
        o.z = nms_px(t.z, row_int,           u.y, u.z, u.w,  c.y, c.z, c.w,  d.y, d.z, d.w);
        o.w = nms_px(t.w, row_int && c3_int, u.z, u.w, uR,   c.z, c.w, cR,   d.z, d.w, dR);

        bstore4_nt(rout, x * rowb + y4 * 4, o);
    }

    // ---- wait: all loads done (only the 4 half0 stores remain in flight) ----
    asm volatile("s_waitcnt vmcnt(4)" ::: "memory");
    __builtin_amdgcn_sched_barrier(0);

    // ---- half1: rows x0+4..x0+7 (uses r/e idx 4..9) ----
    #pragma unroll
    for (int i = 4; i < 8; ++i) {
        const int x = x0 + i;
        const floatx4 u = r[i],   c = r[i + 1], d = r[i + 2];
        const float  ue = e[i],  ce = e[i + 1], de = e[i + 2];
        const floatx4 t = th[i];

        const float uLs = __shfl_up(u.w, 1, 64), uRs = __shfl_down(u.x, 1, 64);
        const float cLs = __shfl_up(c.w, 1, 64), cRs = __shfl_down(c.x, 1, 64);
        const float dLs = __shfl_up(d.w, 1, 64), dRs = __shfl_down(d.x, 1, 64);
        const float uL = is_l ? ue : uLs, uR = is_r ? ue : uRs;
        const float cL = is_l ? ce : cLs, cR = is_r ? ce : cRs;
        const float dL = is_l ? de : dLs, dR = is_r ? de : dRs;

        const bool row_int = (x > 0) && (x < IMG_H - 1);

        floatx4 o;
        o.x = nms_px(t.x, row_int && c0_int, uL,  u.x, u.y,  cL,  c.x, c.y,  dL,  d.x, d.y);
        o.y = nms_px(t.y, row_int,           u.x, u.y, u.z,  c.x, c.y, c.z,  d.x, d.y, d.z);
        o.z = nms_px(t.z, row_int,           u.y, u.z, u.w,  c.y, c.z, c.w,  d.y, d.z, d.w);
        o.w = nms_px(t.w, row_int && c3_int, u.z, u.w, uR,   c.z, c.w, cR,   d.z, d.w, dR);

        bstore4_nt(rout, x * rowb + y4 * 4, o);
    }
}

extern "C" void kernel_launch(void* const* d_in, const int* in_sizes, int n_in,
                              void* d_out, int out_size, void* d_ws, size_t ws_size,
                              hipStream_t stream) {
    const float* img   = (const float*)d_in[0];
    const float* theta = (const float*)d_in[1];
    float* out = (float*)d_out;

    const int total_threads = (IMG_H / RPT) * WPR * 64;  // 512 * 16 * 64
    const int block = 256;
    const int grid = total_threads / block;               // 2048
    nms_kernel<<<grid, block, 0, stream>>>(img, theta, out);
}